// Round 11
// baseline (17807.047 us; speedup 1.0000x reference)
//
#include <hip/hip_runtime.h>
#include <hip/hip_bf16.h>

#define T_ 64
#define B_ 64
#define E_ 512
#define H_ 1024
#define V_ 10000
#define TB 4096   // T_*B_
#define BH 65536  // B_*H_

typedef unsigned short u16;
typedef unsigned int u32;
typedef unsigned long long u64;
typedef __attribute__((ext_vector_type(8))) short short8v;
typedef __attribute__((ext_vector_type(4))) float f32x4;

__device__ inline f32x4 mfma_bf16(short8v a, short8v b, f32x4 c) {
  return __builtin_amdgcn_mfma_f32_16x16x32_bf16(a, b, c, 0, 0, 0);
}

__device__ inline u16 f2bf(float f) {
  unsigned u = __float_as_uint(f);
  unsigned r = (u + 0x7fffu + ((u >> 16) & 1u)) >> 16;
  return (u16)r;
}
__device__ inline float bf2f(u16 h) { return __uint_as_float(((unsigned)h) << 16); }

// ---------------- prep ----------------

__global__ void k_prepall(const float* __restrict__ Wr0, const float* __restrict__ Wz0,
                          const float* __restrict__ Wh0, const float* __restrict__ Ur,
                          const float* __restrict__ Uz, const float* __restrict__ Uh,
                          const float* __restrict__ WrR, const float* __restrict__ WzR,
                          const float* __restrict__ WhR, const float* __restrict__ Wout,
                          u16* __restrict__ W0cat, u16* __restrict__ U0cat,
                          u16* __restrict__ U1W, u16* __restrict__ Woutb) {
  const int HE = H_ * E_;
  const int HH = H_ * H_;
  const size_t n0 = 3u * (size_t)HE;
  const size_t n1 = n0 + 3u * (size_t)HH;
  const size_t n2 = n1 + 3072u * 2048u;
  const size_t n3 = n2 + (size_t)V_ * H_;
  size_t i = (size_t)blockIdx.x * 256 + threadIdx.x;
  const size_t stride = (size_t)gridDim.x * 256;
  for (; i < n3; i += stride) {
    if (i < n0) {
      int g = (int)(i >> 19), off = (int)(i & (HE - 1));
      const float* s = g == 0 ? Wr0 : (g == 1 ? Wz0 : Wh0);
      W0cat[i] = f2bf(s[off]);
    } else if (i < n1) {
      size_t j = i - n0;
      int g = (int)(j >> 20), off = (int)(j & (HH - 1));
      const float* s = g == 0 ? Ur : (g == 1 ? Uz : Uh);
      U0cat[j] = f2bf(s[off]);
    } else if (i < n2) {
      size_t k = i - n1;
      int row = (int)(k >> 11), kk = (int)(k & 2047);
      int g = row >> 10, jj = row & 1023;
      const float* su = g == 0 ? Ur : (g == 1 ? Uz : Uh);
      const float* sw = g == 0 ? WrR : (g == 1 ? WzR : WhR);
      float v = (kk < 1024) ? su[(size_t)HH + (size_t)jj * 1024 + kk]
                            : sw[(size_t)jj * 1024 + (kk - 1024)];
      U1W[k] = f2bf(v);
    } else {
      size_t m = i - n2;
      Woutb[m] = f2bf(Wout[m]);
    }
  }
}

__global__ void k_gather(const int* __restrict__ idx, const float* __restrict__ emb,
                         u16* __restrict__ xbf) {
  int i = blockIdx.x * 256 + threadIdx.x;
  int row = i >> 9, e = i & 511;
  xbf[i] = f2bf(emb[(size_t)idx[row] * E_ + e]);
}

__global__ void k_bias(const float* __restrict__ bur, const float* __restrict__ buz,
                       const float* __restrict__ buh, const float* __restrict__ brR,
                       const float* __restrict__ bzR, const float* __restrict__ bhR,
                       float* __restrict__ bias0, float* __restrict__ bias1) {
  int j = blockIdx.x * 256 + threadIdx.x;
  int seg = j >> 10, col = j & 1023;
  float b0, b1;
  if (seg == 0)      { b0 = bur[col]; b1 = brR[col] + bur[H_ + col]; }
  else if (seg == 1) { b0 = buz[col]; b1 = bzR[col] + buz[H_ + col]; }
  else               { b0 = buh[col]; b1 = bhR[col] + buh[H_ + col]; }
  bias0[j] = b0; bias1[j] = b1;
}

// init packed hist slabs at t=0: dst[(j>>4)*1024 + row*16 + (j&15)]
__global__ void k_init(const float* __restrict__ hidden, u16* __restrict__ h0P,
                       u16* __restrict__ h1P) {
  int i = blockIdx.x * 256 + threadIdx.x;
  int row = i >> 10, j = i & 1023;
  int dst = ((j >> 4) << 10) + (row << 4) + (j & 15);
  h0P[dst] = f2bf(hidden[i]);
  h1P[dst] = f2bf(hidden[BH + i]);
}

// ---------------- GEMM 1: X = x_emb @ W0cat^T + bias0, packed-X bf16 out ----------------

__global__ __launch_bounds__(256, 2) void k_gemmX(const u16* __restrict__ A,
                                                  const u16* __restrict__ Wt,
                                                  const float* __restrict__ bias,
                                                  u16* __restrict__ XP) {
  const int m0 = blockIdx.x * 128, n0 = blockIdx.y * 128;
  const int wid = threadIdx.x >> 6, lane = threadIdx.x & 63;
  const int wm = wid >> 1, wn = wid & 1;
  const int lrow = lane & 15, lk = (lane >> 4) * 8;
  f32x4 acc[4][4] = {};
  const u16* Ab = A + (size_t)(m0 + wm * 64 + lrow) * 512 + lk;
  const u16* Wb = Wt + (size_t)(n0 + wn * 64 + lrow) * 512 + lk;
  for (int ks = 0; ks < 512; ks += 32) {
    short8v a[4], b[4];
#pragma unroll
    for (int f = 0; f < 4; f++) a[f] = *(const short8v*)(Ab + (size_t)f * 16 * 512 + ks);
#pragma unroll
    for (int f = 0; f < 4; f++) b[f] = *(const short8v*)(Wb + (size_t)f * 16 * 512 + ks);
#pragma unroll
    for (int i = 0; i < 4; i++)
#pragma unroll
      for (int j = 0; j < 4; j++) acc[i][j] = mfma_bf16(a[i], b[j], acc[i][j]);
  }
  const int drow0 = (lane >> 4) * 4, dcol = lane & 15;
#pragma unroll
  for (int i = 0; i < 4; i++)
#pragma unroll
    for (int j = 0; j < 4; j++) {
      int col = n0 + wn * 64 + j * 16 + dcol;
      float bv = bias[col];
      int g = col >> 10, cg = (col & 1023) >> 4, cc = col & 15;
#pragma unroll
      for (int v = 0; v < 4; v++) {
        int row = m0 + wm * 64 + i * 16 + drow0 + v;
        int t = row >> 6, rr = row & 63;
        XP[(((size_t)t * 64 + cg) * 64 + rr) * 48 + g * 16 + cc] = f2bf(acc[i][j][v] + bv);
      }
    }
}

// ---------------- GEMM 2: logits, XCD-affine N-partitioning ----------------

__global__ __launch_bounds__(256, 2) void k_gemmL(const u16* __restrict__ AP,
                                                  const u16* __restrict__ Wt,
                                                  const float* __restrict__ bias,
                                                  float* __restrict__ C) {
  const int xcd = blockIdx.x & 7, idx = blockIdx.x >> 3;
  const int nt = xcd * 10 + (idx % 10);
  const int mt = idx / 10;
  if (nt >= 79) return;
  const int m0 = mt * 128, n0 = nt * 128;
  const int wid = threadIdx.x >> 6, lane = threadIdx.x & 63;
  const int wm = wid >> 1, wn = wid & 1;
  const int lrow = lane & 15, lk = (lane >> 4) * 8;
  const int lkb = lk >> 4, lkc = lk & 15;
  f32x4 acc[4][4] = {};
  const int rowhi = (m0 + wm * 64) >> 6;
  const u16* Ab = AP + (size_t)rowhi * BH + (size_t)lkb * 1024 + lrow * 16 + lkc;
  const u16* Wb = Wt + (size_t)(n0 + wn * 64 + lrow) * 1024 + lk;
  bool nvalid[4];
#pragma unroll
  for (int f = 0; f < 4; f++) nvalid[f] = (n0 + wn * 64 + f * 16 + lrow) < V_;
  const short8v zv = {};
  for (int ks = 0; ks < 1024; ks += 32) {
    short8v a[4], b[4];
#pragma unroll
    for (int f = 0; f < 4; f++) a[f] = *(const short8v*)(Ab + ks * 64 + f * 256);
#pragma unroll
    for (int f = 0; f < 4; f++)
      b[f] = nvalid[f] ? *(const short8v*)(Wb + (size_t)f * 16 * 1024 + ks) : zv;
#pragma unroll
    for (int i = 0; i < 4; i++)
#pragma unroll
      for (int j = 0; j < 4; j++) acc[i][j] = mfma_bf16(a[i], b[j], acc[i][j]);
  }
  const int drow0 = (lane >> 4) * 4, dcol = lane & 15;
#pragma unroll
  for (int i = 0; i < 4; i++)
#pragma unroll
    for (int j = 0; j < 4; j++) {
      int col = n0 + wn * 64 + j * 16 + dcol;
      if (col >= V_) continue;
      float bv = bias[col];
#pragma unroll
      for (int v = 0; v < 4; v++) {
        int row = m0 + wm * 64 + i * 16 + drow0 + v;
        C[(size_t)row * V_ + col] = acc[i][j][v] + bv;
      }
    }
}

// ---------------- recurrence (R8 structure) + shadow ablation variant ----------------
// SHADOW=0: exact R8 behavior (slot-store signaling + aggregator broadcast).
// SHADOW=1: ablation — identical data path (same slab addressing, publishes, vmcnt
// drains, LDS/MFMA work), ALL flag stores/polls removed, 8 reps, separate slabs.

__device__ inline void waitge(int* c, int tgt) {
  while (__hip_atomic_load(c, __ATOMIC_RELAXED, __HIP_MEMORY_SCOPE_AGENT) < tgt)
    __builtin_amdgcn_s_sleep(1);
}

template <int SHADOW>
__device__ __forceinline__ void recur_body(
    const u16* __restrict__ U0, const u16* __restrict__ U1W,
    const u16* __restrict__ XP, const float* __restrict__ bias1,
    const float* __restrict__ hidden,
    u16* __restrict__ h0P, u16* __restrict__ h1P,
    u16* __restrict__ r0P, u16* __restrict__ r1P,
    int* __restrict__ flags, float* __restrict__ hfin, u16* wlds) {
  const int tid = threadIdx.x, gbid = blockIdx.x;
  int* bcast0 = flags + 4096;
  int* bcast1 = flags + 4128;

  if (gbid >= 128) {
    if constexpr (SHADOW) return;
    // ---------- aggregator: one wave, lane i watches slot i ----------
    const int layA = gbid - 128;
    int* slots = flags + layA * 2048;
    int* bc = layA ? bcast1 : bcast0;
    if (tid < 64) {
      int* myslot = slots + tid * 32;
      int last = 0;
      for (int ph = 1; ph <= 2 * T_; ph++) {
        while (last < ph) {
          last = __hip_atomic_load(myslot, __ATOMIC_RELAXED, __HIP_MEMORY_SCOPE_AGENT);
          if (last < ph) __builtin_amdgcn_s_sleep(1);
        }
        if (tid == 0)
          __hip_atomic_store(bc, ph, __ATOMIC_RELAXED, __HIP_MEMORY_SCOPE_AGENT);
      }
    }
    return;
  }

  const int lay = gbid >> 6;
  const int cg = gbid & 63;
  const int jr = cg * 16;
  const int wid = tid >> 6, lane = tid & 63;
  const int lrow = lane & 15, lk = (lane >> 4) * 8;
  const int lk3 = lk >> 3, x7 = lrow & 7;
  const int drow0 = (lane >> 4) * 4, dcol = lane & 15;
  const int abase = (lk >> 4) * 1024 + (wid * 16 + lrow) * 16 + (lk & 15);
  const int KLS = lay ? 11 : 10;
  int* myslot = flags + lay * 2048 + cg * 32;

  {  // stage weights into LDS (swizzled 16B chunks)
    const u16* Wg = lay ? U1W : U0;
    const int lCPR = lay ? 8 : 7;
    const int NG = lay ? 2 : 3;
    const int total = NG << (4 + lCPR);
    const int KL = 1 << KLS;
    for (int idx = tid; idx < total; idx += 256) {
      int r16 = idx >> lCPR;
      int ch = idx & ((1 << lCPR) - 1);
      int g = r16 >> 4, r = r16 & 15;
      short8v v = *(const short8v*)(Wg + (size_t)((g << 10) + jr + r) * KL + (ch << 3));
      *(short8v*)&wlds[((size_t)r16 << KLS) + ((ch ^ (r & 7)) << 3)] = v;
    }
  }
  __syncthreads();

  const int lbR = lrow << KLS;
  const int lbZ = (16 + lrow) << KLS;
  const int lbH = (32 + lrow) << KLS;  // L0 only
  const u16* Whg = U1W + (size_t)(2048 + jr + lrow) * 2048 + lk;  // L1 Wh (global)
  const int orow = wid * 16 + drow0;

  float hreg[4];
#pragma unroll
  for (int v = 0; v < 4; v++)
    hreg[v] = hidden[(size_t)lay * BH + (size_t)(orow + v) * 1024 + jr + dcol];

  const int REPS = SHADOW ? 8 : 1;
  if (!lay) {
    // ================= layer 0 =================
    for (int rep = 0; rep < REPS; rep++)
    for (int t = 0; t < T_; t++) {
      float xr[4], xz[4], xh[4], zreg[4];
      const u16* xb = XP + (((size_t)t * 64 + cg) * 64 + orow) * 48 + dcol;
#pragma unroll
      for (int v = 0; v < 4; v++) {
        xr[v] = bf2f(xb[v * 48]);
        xz[v] = bf2f(xb[v * 48 + 16]);
        xh[v] = bf2f(xb[v * 48 + 32]);
      }
      if (t) {
        if constexpr (!SHADOW) { if (tid == 0) waitge(bcast0, 2 * t); }
        __syncthreads();
      }
      // stage A
      f32x4 ar = {}, az = {};
      const u16* Ab = h0P + (size_t)t * BH + abase;
#pragma unroll
      for (int kk = 0; kk < 1024; kk += 32) {
        short8v a = *(const short8v*)(Ab + kk * 64);
        const int sw = (((kk >> 3) + lk3) ^ x7) << 3;
        ar = mfma_bf16(a, *(short8v*)&wlds[lbR + sw], ar);
        az = mfma_bf16(a, *(short8v*)&wlds[lbZ + sw], az);
      }
      u16* rtile = r0P + (size_t)t * BH + (size_t)cg * 1024;
#pragma unroll
      for (int v = 0; v < 4; v++) {
        float r = 1.f / (1.f + __expf(-(ar[v] + xr[v])));
        float z = 1.f / (1.f + __expf(-(az[v] + xz[v])));
        zreg[v] = z;
        u16 me = f2bf(r * hreg[v]);
        int oth = __shfl_xor((int)me, 1);
        if (!(dcol & 1)) {
          u32 pk = (u32)me | ((u32)(u16)oth << 16);
          __hip_atomic_store((u32*)(rtile + (orow + v) * 16 + dcol), pk,
                             __ATOMIC_RELAXED, __HIP_MEMORY_SCOPE_AGENT);
        }
      }
      asm volatile("s_waitcnt vmcnt(0)" ::: "memory");
      __syncthreads();
      if constexpr (!SHADOW) {
        if (tid == 0) {
          __hip_atomic_store(myslot, 2 * t + 1, __ATOMIC_RELAXED, __HIP_MEMORY_SCOPE_AGENT);
          waitge(bcast0, 2 * t + 1);
        }
      }
      __syncthreads();
      // stage B
      f32x4 ah = {};
      const u16* Abr = r0P + (size_t)t * BH + abase;
#pragma unroll
      for (int kk = 0; kk < 1024; kk += 32) {
        short8v a = *(const short8v*)(Abr + kk * 64);
        const int sw = (((kk >> 3) + lk3) ^ x7) << 3;
        ah = mfma_bf16(a, *(short8v*)&wlds[lbH + sw], ah);
      }
      u16* htile = h0P + (size_t)(t + 1) * BH + (size_t)cg * 1024;
#pragma unroll
      for (int v = 0; v < 4; v++) {
        float th = tanhf(ah[v] + xh[v]);
        float hn = (1.f - zreg[v]) * hreg[v] + zreg[v] * th;
        hreg[v] = hn;
        u16 me = f2bf(hn);
        int oth = __shfl_xor((int)me, 1);
        if (!(dcol & 1)) {
          u32 pk = (u32)me | ((u32)(u16)oth << 16);
          __hip_atomic_store((u32*)(htile + (orow + v) * 16 + dcol), pk,
                             __ATOMIC_RELAXED, __HIP_MEMORY_SCOPE_AGENT);
        }
        if (t == T_ - 1)
          hfin[(size_t)(orow + v) * 1024 + jr + dcol] = hn;
      }
      asm volatile("s_waitcnt vmcnt(0)" ::: "memory");
      __syncthreads();
      if constexpr (!SHADOW) {
        if (tid == 0)
          __hip_atomic_store(myslot, 2 * t + 2, __ATOMIC_RELAXED, __HIP_MEMORY_SCOPE_AGENT);
      }
    }
  } else {
    // ================= layer 1 =================
    float bR = bias1[jr + dcol];
    float bZ = bias1[1024 + jr + dcol];
    float bH = bias1[2048 + jr + dcol];
    if constexpr (!SHADOW) { if (tid == 0) waitge(bcast0, 2); }
    __syncthreads();
    for (int rep = 0; rep < REPS; rep++)
    for (int t = 0; t < T_; t++) {
      float zreg[4];
      // ---- A part 1: h0[t+1] half ----
      f32x4 ar = {}, az = {};
      const u16* Ab0 = h0P + (size_t)(t + 1) * BH + abase;
#pragma unroll
      for (int kk = 0; kk < 1024; kk += 32) {
        short8v a = *(const short8v*)(Ab0 + kk * 64);
        const int sw = ((128 + (kk >> 3) + lk3) ^ x7) << 3;
        ar = mfma_bf16(a, *(short8v*)&wlds[lbR + sw], ar);
        az = mfma_bf16(a, *(short8v*)&wlds[lbZ + sw], az);
      }
      // ---- wait: h1[t] visible; keep L0 2 steps ahead ----
      if constexpr (!SHADOW) {
        if (tid == 0) {
          if (t) waitge(bcast1, 2 * t);
          int tgt = 2 * (t + 2);
          waitge(bcast0, tgt > 2 * T_ ? 2 * T_ : tgt);
        }
      }
      __syncthreads();
      // ---- A part 2: h1[t] half ----
      const u16* Ab1 = h1P + (size_t)t * BH + abase;
#pragma unroll
      for (int kk = 0; kk < 1024; kk += 32) {
        short8v a = *(const short8v*)(Ab1 + kk * 64);
        const int sw = (((kk >> 3) + lk3) ^ x7) << 3;
        ar = mfma_bf16(a, *(short8v*)&wlds[lbR + sw], ar);
        az = mfma_bf16(a, *(short8v*)&wlds[lbZ + sw], az);
      }
      u16* rtile = r1P + (size_t)t * BH + (size_t)cg * 1024;
#pragma unroll
      for (int v = 0; v < 4; v++) {
        float r = 1.f / (1.f + __expf(-(ar[v] + bR)));
        float z = 1.f / (1.f + __expf(-(az[v] + bZ)));
        zreg[v] = z;
        u16 me = f2bf(r * hreg[v]);
        int oth = __shfl_xor((int)me, 1);
        if (!(dcol & 1)) {
          u32 pk = (u32)me | ((u32)(u16)oth << 16);
          __hip_atomic_store((u32*)(rtile + (orow + v) * 16 + dcol), pk,
                             __ATOMIC_RELAXED, __HIP_MEMORY_SCOPE_AGENT);
        }
      }
      asm volatile("s_waitcnt vmcnt(0)" ::: "memory");
      __syncthreads();
      if constexpr (!SHADOW) {
        if (tid == 0)
          __hip_atomic_store(myslot, 2 * t + 1, __ATOMIC_RELAXED, __HIP_MEMORY_SCOPE_AGENT);
      }
      // ---- B part 1: h0[t+1] half ----
      f32x4 ah = {};
#pragma unroll
      for (int kk = 0; kk < 1024; kk += 32) {
        short8v a = *(const short8v*)(Ab0 + kk * 64);
        short8v b = *(const short8v*)(Whg + 1024 + kk);
        ah = mfma_bf16(a, b, ah);
      }
      // ---- wait: rh1[t] visible ----
      if constexpr (!SHADOW) { if (tid == 0) waitge(bcast1, 2 * t + 1); }
      __syncthreads();
      // ---- B part 2: rh1[t] half ----
      const u16* Abr = r1P + (size_t)t * BH + abase;
#pragma unroll
      for (int kk = 0; kk < 1024; kk += 32) {
        short8v a = *(const short8v*)(Abr + kk * 64);
        short8v b = *(const short8v*)(Whg + kk);
        ah = mfma_bf16(a, b, ah);
      }
      u16* htile = h1P + (size_t)(t + 1) * BH + (size_t)cg * 1024;
#pragma unroll
      for (int v = 0; v < 4; v++) {
        float th = tanhf(ah[v] + bH);
        float hn = (1.f - zreg[v]) * hreg[v] + zreg[v] * th;
        hreg[v] = hn;
        u16 me = f2bf(hn);
        int oth = __shfl_xor((int)me, 1);
        if (!(dcol & 1)) {
          u32 pk = (u32)me | ((u32)(u16)oth << 16);
          __hip_atomic_store((u32*)(htile + (orow + v) * 16 + dcol), pk,
                             __ATOMIC_RELAXED, __HIP_MEMORY_SCOPE_AGENT);
        }
        if (t == T_ - 1)
          hfin[(size_t)BH + (size_t)(orow + v) * 1024 + jr + dcol] = hn;
      }
      asm volatile("s_waitcnt vmcnt(0)" ::: "memory");
      __syncthreads();
      if constexpr (!SHADOW) {
        if (tid == 0)
          __hip_atomic_store(myslot, 2 * t + 2, __ATOMIC_RELAXED, __HIP_MEMORY_SCOPE_AGENT);
      }
    }
  }
}

__global__ __launch_bounds__(256, 1) void k_recur(
    const u16* __restrict__ U0, const u16* __restrict__ U1W,
    const u16* __restrict__ XP, const float* __restrict__ bias1,
    const float* __restrict__ hidden,
    u16* __restrict__ h0P, u16* __restrict__ h1P,
    u16* __restrict__ r0P, u16* __restrict__ r1P,
    int* __restrict__ flags, float* __restrict__ hfin) {
  __shared__ __align__(16) u16 wlds[65536];
  recur_body<0>(U0, U1W, XP, bias1, hidden, h0P, h1P, r0P, r1P, flags, hfin, wlds);
}

__global__ __launch_bounds__(256, 1) void k_shadow(
    const u16* __restrict__ U0, const u16* __restrict__ U1W,
    const u16* __restrict__ XP, const float* __restrict__ bias1,
    const float* __restrict__ hidden,
    u16* __restrict__ h0P, u16* __restrict__ h1P,
    u16* __restrict__ r0P, u16* __restrict__ r1P,
    int* __restrict__ flags, float* __restrict__ hfin) {
  __shared__ __align__(16) u16 wlds[65536];
  recur_body<1>(U0, U1W, XP, bias1, hidden, h0P, h1P, r0P, r1P, flags, hfin, wlds);
}

// ---------------- launcher ----------------

extern "C" void kernel_launch(void* const* d_in, const int* in_sizes, int n_in,
                              void* d_out, int out_size, void* d_ws, size_t ws_size,
                              hipStream_t stream) {
  const int* inputs = (const int*)d_in[0];
  const float* hidden = (const float*)d_in[1];
  const float* emb = (const float*)d_in[2];
  const float* Wr0 = (const float*)d_in[3];
  const float* Wz0 = (const float*)d_in[4];
  const float* Wh0 = (const float*)d_in[5];
  const float* WrR = (const float*)d_in[6];
  const float* WzR = (const float*)d_in[7];
  const float* WhR = (const float*)d_in[8];
  const float* brR = (const float*)d_in[9];
  const float* bzR = (const float*)d_in[10];
  const float* bhR = (const float*)d_in[11];
  const float* Ur = (const float*)d_in[12];
  const float* Uz = (const float*)d_in[13];
  const float* Uh = (const float*)d_in[14];
  const float* bur = (const float*)d_in[15];
  const float* buz = (const float*)d_in[16];
  const float* buh = (const float*)d_in[17];
  const float* Wout = (const float*)d_in[18];
  const float* bout = (const float*)d_in[19];
  float* out = (float*)d_out;

  char* ws = (char*)d_ws;
  size_t off = 0;
  auto alloc = [&](size_t bytes) -> void* {
    void* p = ws + off;
    off += (bytes + 255) & ~(size_t)255;
    return p;
  };
  u16* x_bf  = (u16*)alloc((size_t)TB * E_ * 2);
  u16* W0cat = (u16*)alloc((size_t)3072 * 512 * 2);
  u16* U0cat = (u16*)alloc((size_t)3072 * 1024 * 2);
  u16* U1W   = (u16*)alloc((size_t)3072 * 2048 * 2);
  u16* Woutb = (u16*)alloc((size_t)V_ * H_ * 2);
  float* bias0 = (float*)alloc(3072 * 4);
  float* bias1 = (float*)alloc(3072 * 4);
  u16* XP    = (u16*)alloc((size_t)TB * 3072 * 2);
  u16* h0P   = (u16*)alloc((size_t)(T_ + 1) * BH * 2);
  u16* h1P   = (u16*)alloc((size_t)(T_ + 1) * BH * 2);
  u16* r0P   = (u16*)alloc((size_t)T_ * BH * 2);
  u16* r1P   = (u16*)alloc((size_t)T_ * BH * 2);
  int* flags = (int*)alloc(32768);
  // shadow slabs (ablation only; never read by real kernels)
  u16* sh0P  = (u16*)alloc((size_t)(T_ + 1) * BH * 2);
  u16* sh1P  = (u16*)alloc((size_t)(T_ + 1) * BH * 2);
  u16* sr0P  = (u16*)alloc((size_t)T_ * BH * 2);
  u16* sr1P  = (u16*)alloc((size_t)T_ * BH * 2);
  float* shfin = (float*)alloc((size_t)2 * BH * 4);
  (void)ws_size; (void)in_sizes; (void)n_in; (void)out_size;

  hipMemsetAsync(flags, 0, 32768, stream);

  k_prepall<<<2048, 256, 0, stream>>>(Wr0, Wz0, Wh0, Ur, Uz, Uh, WrR, WzR, WhR, Wout,
                                      W0cat, U0cat, U1W, Woutb);
  k_gather<<<TB * E_ / 256, 256, 0, stream>>>(inputs, emb, x_bf);
  k_bias<<<12, 256, 0, stream>>>(bur, buz, buh, brR, bzR, bhR, bias0, bias1);
  k_init<<<256, 256, 0, stream>>>(hidden, h0P, h1P);

  k_gemmX<<<dim3(32, 24), 256, 0, stream>>>(x_bf, W0cat, bias0, XP);
  // ablation shadow: data path only, no sync, 8 reps, separate slabs
  k_shadow<<<130, 256, 0, stream>>>(U0cat, U1W, XP, bias1, hidden, sh0P, sh1P,
                                    sr0P, sr1P, flags, shfin);
  // real recurrence (R8 structure, unchanged)
  k_recur<<<130, 256, 0, stream>>>(U0cat, U1W, XP, bias1, hidden, h0P, h1P,
                                   r0P, r1P, flags, out + (size_t)TB * V_);
  k_gemmL<<<2560, 256, 0, stream>>>(h1P + BH, Woutb, bout, out);
}

// Round 12
// 1469.082 us; speedup vs baseline: 12.1212x; 12.1212x over previous
//
#include <hip/hip_runtime.h>
#include <hip/hip_bf16.h>

#define T_ 64
#define B_ 64
#define E_ 512
#define H_ 1024
#define V_ 10000
#define TB 4096   // T_*B_
#define BH 65536  // B_*H_

typedef unsigned short u16;
typedef unsigned int u32;
typedef unsigned long long u64;
typedef __attribute__((ext_vector_type(8))) short short8v;
typedef __attribute__((ext_vector_type(4))) float f32x4;

__device__ inline f32x4 mfma_bf16(short8v a, short8v b, f32x4 c) {
  return __builtin_amdgcn_mfma_f32_16x16x32_bf16(a, b, c, 0, 0, 0);
}

__device__ inline u16 f2bf(float f) {
  unsigned u = __float_as_uint(f);
  unsigned r = (u + 0x7fffu + ((u >> 16) & 1u)) >> 16;
  return (u16)r;
}
__device__ inline float bf2f(u16 h) { return __uint_as_float(((unsigned)h) << 16); }

// ---------------- prep ----------------

__global__ void k_prepall(const float* __restrict__ Wr0, const float* __restrict__ Wz0,
                          const float* __restrict__ Wh0, const float* __restrict__ Ur,
                          const float* __restrict__ Uz, const float* __restrict__ Uh,
                          const float* __restrict__ WrR, const float* __restrict__ WzR,
                          const float* __restrict__ WhR, const float* __restrict__ Wout,
                          u16* __restrict__ W0cat, u16* __restrict__ U0cat,
                          u16* __restrict__ U1W, u16* __restrict__ Woutb) {
  const int HE = H_ * E_;
  const int HH = H_ * H_;
  const size_t n0 = 3u * (size_t)HE;
  const size_t n1 = n0 + 3u * (size_t)HH;
  const size_t n2 = n1 + 3072u * 2048u;
  const size_t n3 = n2 + (size_t)V_ * H_;
  size_t i = (size_t)blockIdx.x * 256 + threadIdx.x;
  const size_t stride = (size_t)gridDim.x * 256;
  for (; i < n3; i += stride) {
    if (i < n0) {
      int g = (int)(i >> 19), off = (int)(i & (HE - 1));
      const float* s = g == 0 ? Wr0 : (g == 1 ? Wz0 : Wh0);
      W0cat[i] = f2bf(s[off]);
    } else if (i < n1) {
      size_t j = i - n0;
      int g = (int)(j >> 20), off = (int)(j & (HH - 1));
      const float* s = g == 0 ? Ur : (g == 1 ? Uz : Uh);
      U0cat[j] = f2bf(s[off]);
    } else if (i < n2) {
      size_t k = i - n1;
      int row = (int)(k >> 11), kk = (int)(k & 2047);
      int g = row >> 10, jj = row & 1023;
      const float* su = g == 0 ? Ur : (g == 1 ? Uz : Uh);
      const float* sw = g == 0 ? WrR : (g == 1 ? WzR : WhR);
      float v = (kk < 1024) ? su[(size_t)HH + (size_t)jj * 1024 + kk]
                            : sw[(size_t)jj * 1024 + (kk - 1024)];
      U1W[k] = f2bf(v);
    } else {
      size_t m = i - n2;
      Woutb[m] = f2bf(Wout[m]);
    }
  }
}

__global__ void k_gather(const int* __restrict__ idx, const float* __restrict__ emb,
                         u16* __restrict__ xbf) {
  int i = blockIdx.x * 256 + threadIdx.x;
  int row = i >> 9, e = i & 511;
  xbf[i] = f2bf(emb[(size_t)idx[row] * E_ + e]);
}

__global__ void k_bias(const float* __restrict__ bur, const float* __restrict__ buz,
                       const float* __restrict__ buh, const float* __restrict__ brR,
                       const float* __restrict__ bzR, const float* __restrict__ bhR,
                       float* __restrict__ bias0, float* __restrict__ bias1) {
  int j = blockIdx.x * 256 + threadIdx.x;
  int seg = j >> 10, col = j & 1023;
  float b0, b1;
  if (seg == 0)      { b0 = bur[col]; b1 = brR[col] + bur[H_ + col]; }
  else if (seg == 1) { b0 = buz[col]; b1 = bzR[col] + buz[H_ + col]; }
  else               { b0 = buh[col]; b1 = bhR[col] + buh[H_ + col]; }
  bias0[j] = b0; bias1[j] = b1;
}

// init packed hist slabs at t=0: dst[(j>>4)*1024 + row*16 + (j&15)]
__global__ void k_init(const float* __restrict__ hidden, u16* __restrict__ h0P,
                       u16* __restrict__ h1P) {
  int i = blockIdx.x * 256 + threadIdx.x;
  int row = i >> 10, j = i & 1023;
  int dst = ((j >> 4) << 10) + (row << 4) + (j & 15);
  h0P[dst] = f2bf(hidden[i]);
  h1P[dst] = f2bf(hidden[BH + i]);
}

// ---------------- GEMM 1: X = x_emb @ W0cat^T + bias0, packed-X bf16 out ----------------

__global__ __launch_bounds__(256, 2) void k_gemmX(const u16* __restrict__ A,
                                                  const u16* __restrict__ Wt,
                                                  const float* __restrict__ bias,
                                                  u16* __restrict__ XP) {
  const int m0 = blockIdx.x * 128, n0 = blockIdx.y * 128;
  const int wid = threadIdx.x >> 6, lane = threadIdx.x & 63;
  const int wm = wid >> 1, wn = wid & 1;
  const int lrow = lane & 15, lk = (lane >> 4) * 8;
  f32x4 acc[4][4] = {};
  const u16* Ab = A + (size_t)(m0 + wm * 64 + lrow) * 512 + lk;
  const u16* Wb = Wt + (size_t)(n0 + wn * 64 + lrow) * 512 + lk;
  for (int ks = 0; ks < 512; ks += 32) {
    short8v a[4], b[4];
#pragma unroll
    for (int f = 0; f < 4; f++) a[f] = *(const short8v*)(Ab + (size_t)f * 16 * 512 + ks);
#pragma unroll
    for (int f = 0; f < 4; f++) b[f] = *(const short8v*)(Wb + (size_t)f * 16 * 512 + ks);
#pragma unroll
    for (int i = 0; i < 4; i++)
#pragma unroll
      for (int j = 0; j < 4; j++) acc[i][j] = mfma_bf16(a[i], b[j], acc[i][j]);
  }
  const int drow0 = (lane >> 4) * 4, dcol = lane & 15;
#pragma unroll
  for (int i = 0; i < 4; i++)
#pragma unroll
    for (int j = 0; j < 4; j++) {
      int col = n0 + wn * 64 + j * 16 + dcol;
      float bv = bias[col];
      int g = col >> 10, cg = (col & 1023) >> 4, cc = col & 15;
#pragma unroll
      for (int v = 0; v < 4; v++) {
        int row = m0 + wm * 64 + i * 16 + drow0 + v;
        int t = row >> 6, rr = row & 63;
        XP[(((size_t)t * 64 + cg) * 64 + rr) * 48 + g * 16 + cc] = f2bf(acc[i][j][v] + bv);
      }
    }
}

// ---------------- GEMM 2: logits, XCD-affine N-partitioning ----------------

__global__ __launch_bounds__(256, 2) void k_gemmL(const u16* __restrict__ AP,
                                                  const u16* __restrict__ Wt,
                                                  const float* __restrict__ bias,
                                                  float* __restrict__ C) {
  const int xcd = blockIdx.x & 7, idx = blockIdx.x >> 3;
  const int nt = xcd * 10 + (idx % 10);
  const int mt = idx / 10;
  if (nt >= 79) return;
  const int m0 = mt * 128, n0 = nt * 128;
  const int wid = threadIdx.x >> 6, lane = threadIdx.x & 63;
  const int wm = wid >> 1, wn = wid & 1;
  const int lrow = lane & 15, lk = (lane >> 4) * 8;
  const int lkb = lk >> 4, lkc = lk & 15;
  f32x4 acc[4][4] = {};
  const int rowhi = (m0 + wm * 64) >> 6;
  const u16* Ab = AP + (size_t)rowhi * BH + (size_t)lkb * 1024 + lrow * 16 + lkc;
  const u16* Wb = Wt + (size_t)(n0 + wn * 64 + lrow) * 1024 + lk;
  bool nvalid[4];
#pragma unroll
  for (int f = 0; f < 4; f++) nvalid[f] = (n0 + wn * 64 + f * 16 + lrow) < V_;
  const short8v zv = {};
  for (int ks = 0; ks < 1024; ks += 32) {
    short8v a[4], b[4];
#pragma unroll
    for (int f = 0; f < 4; f++) a[f] = *(const short8v*)(Ab + ks * 64 + f * 256);
#pragma unroll
    for (int f = 0; f < 4; f++)
      b[f] = nvalid[f] ? *(const short8v*)(Wb + (size_t)f * 16 * 1024 + ks) : zv;
#pragma unroll
    for (int i = 0; i < 4; i++)
#pragma unroll
      for (int j = 0; j < 4; j++) acc[i][j] = mfma_bf16(a[i], b[j], acc[i][j]);
  }
  const int drow0 = (lane >> 4) * 4, dcol = lane & 15;
#pragma unroll
  for (int i = 0; i < 4; i++)
#pragma unroll
    for (int j = 0; j < 4; j++) {
      int col = n0 + wn * 64 + j * 16 + dcol;
      if (col >= V_) continue;
      float bv = bias[col];
#pragma unroll
      for (int v = 0; v < 4; v++) {
        int row = m0 + wm * 64 + i * 16 + drow0 + v;
        C[(size_t)row * V_ + col] = acc[i][j][v] + bv;
      }
    }
}

// ---------------- recurrence: R8 structure + burst-loaded A-operands ----------------
// 130 blocks x 256 thr. gbid<64: L0 (cg=gbid); 64..127: L1; 128/129: aggregators.
// Key change vs R8: every A-operand kk-loop is split into load-ALL-32-into-registers
// (all HBM loads in flight; 1 block/CU -> 1 wave/SIMD -> up to 512 VGPR) then MFMA-all.
// Signaling identical to R8 (ablation-proven free).

__device__ inline void waitge(int* c, int tgt) {
  while (__hip_atomic_load(c, __ATOMIC_RELAXED, __HIP_MEMORY_SCOPE_AGENT) < tgt)
    __builtin_amdgcn_s_sleep(1);
}

__global__ __launch_bounds__(256, 1) void k_recur(
    const u16* __restrict__ U0, const u16* __restrict__ U1W,
    const u16* __restrict__ XP, const float* __restrict__ bias1,
    const float* __restrict__ hidden,
    u16* __restrict__ h0P, u16* __restrict__ h1P,
    u16* __restrict__ r0P, u16* __restrict__ r1P,
    int* __restrict__ flags, float* __restrict__ hfin) {
  __shared__ __align__(16) u16 wlds[65536];  // 128 KiB

  const int tid = threadIdx.x, gbid = blockIdx.x;
  int* bcast0 = flags + 4096;
  int* bcast1 = flags + 4128;

  if (gbid >= 128) {
    // ---------- aggregator: one wave, lane i watches slot i ----------
    const int layA = gbid - 128;
    int* slots = flags + layA * 2048;
    int* bc = layA ? bcast1 : bcast0;
    if (tid < 64) {
      int* myslot = slots + tid * 32;
      int last = 0;
      for (int ph = 1; ph <= 2 * T_; ph++) {
        while (last < ph) {
          last = __hip_atomic_load(myslot, __ATOMIC_RELAXED, __HIP_MEMORY_SCOPE_AGENT);
          if (last < ph) __builtin_amdgcn_s_sleep(1);
        }
        if (tid == 0)
          __hip_atomic_store(bc, ph, __ATOMIC_RELAXED, __HIP_MEMORY_SCOPE_AGENT);
      }
    }
    return;
  }

  const int lay = gbid >> 6;
  const int cg = gbid & 63;
  const int jr = cg * 16;
  const int wid = tid >> 6, lane = tid & 63;
  const int lrow = lane & 15, lk = (lane >> 4) * 8;
  const int lk3 = lk >> 3, x7 = lrow & 7;
  const int drow0 = (lane >> 4) * 4, dcol = lane & 15;
  const int abase = (lk >> 4) * 1024 + (wid * 16 + lrow) * 16 + (lk & 15);
  const int KLS = lay ? 11 : 10;
  int* myslot = flags + lay * 2048 + cg * 32;

  {  // stage weights into LDS (swizzled 16B chunks)
    const u16* Wg = lay ? U1W : U0;
    const int lCPR = lay ? 8 : 7;
    const int NG = lay ? 2 : 3;
    const int total = NG << (4 + lCPR);
    const int KL = 1 << KLS;
    for (int idx = tid; idx < total; idx += 256) {
      int r16 = idx >> lCPR;
      int ch = idx & ((1 << lCPR) - 1);
      int g = r16 >> 4, r = r16 & 15;
      short8v v = *(const short8v*)(Wg + (size_t)((g << 10) + jr + r) * KL + (ch << 3));
      *(short8v*)&wlds[((size_t)r16 << KLS) + ((ch ^ (r & 7)) << 3)] = v;
    }
  }
  __syncthreads();

  const int lbR = lrow << KLS;
  const int lbZ = (16 + lrow) << KLS;
  const int lbH = (32 + lrow) << KLS;  // L0 only
  const u16* Whg = U1W + (size_t)(2048 + jr + lrow) * 2048 + lk;  // L1 Wh (global)
  const int orow = wid * 16 + drow0;

  float hreg[4];
#pragma unroll
  for (int v = 0; v < 4; v++)
    hreg[v] = hidden[(size_t)lay * BH + (size_t)(orow + v) * 1024 + jr + dcol];

  if (!lay) {
    // ================= layer 0 =================
    for (int t = 0; t < T_; t++) {
      float xr[4], xz[4], xh[4], zreg[4];
      const u16* xb = XP + (((size_t)t * 64 + cg) * 64 + orow) * 48 + dcol;
#pragma unroll
      for (int v = 0; v < 4; v++) {
        xr[v] = bf2f(xb[v * 48]);
        xz[v] = bf2f(xb[v * 48 + 16]);
        xh[v] = bf2f(xb[v * 48 + 32]);
      }
      if (t) { if (tid == 0) waitge(bcast0, 2 * t); __syncthreads(); }
      // stage A: burst-load h0[t], then MFMA
      f32x4 ar = {}, az = {};
      {
        const u16* Ab = h0P + (size_t)t * BH + abase;
        short8v av[32];
#pragma unroll
        for (int i = 0; i < 32; i++) av[i] = *(const short8v*)(Ab + i * 2048);
#pragma unroll
        for (int i = 0; i < 32; i++) {
          const int sw = (((i * 4) + lk3) ^ x7) << 3;
          ar = mfma_bf16(av[i], *(short8v*)&wlds[lbR + sw], ar);
          az = mfma_bf16(av[i], *(short8v*)&wlds[lbZ + sw], az);
        }
      }
      u16* rtile = r0P + (size_t)t * BH + (size_t)cg * 1024;
#pragma unroll
      for (int v = 0; v < 4; v++) {
        float r = 1.f / (1.f + __expf(-(ar[v] + xr[v])));
        float z = 1.f / (1.f + __expf(-(az[v] + xz[v])));
        zreg[v] = z;
        u16 me = f2bf(r * hreg[v]);
        int oth = __shfl_xor((int)me, 1);
        if (!(dcol & 1)) {
          u32 pk = (u32)me | ((u32)(u16)oth << 16);
          __hip_atomic_store((u32*)(rtile + (orow + v) * 16 + dcol), pk,
                             __ATOMIC_RELAXED, __HIP_MEMORY_SCOPE_AGENT);
        }
      }
      asm volatile("s_waitcnt vmcnt(0)" ::: "memory");
      __syncthreads();
      if (tid == 0) {
        __hip_atomic_store(myslot, 2 * t + 1, __ATOMIC_RELAXED, __HIP_MEMORY_SCOPE_AGENT);
        waitge(bcast0, 2 * t + 1);
      }
      __syncthreads();
      // stage B: burst-load rh0[t], then MFMA
      f32x4 ah = {};
      {
        const u16* Abr = r0P + (size_t)t * BH + abase;
        short8v av[32];
#pragma unroll
        for (int i = 0; i < 32; i++) av[i] = *(const short8v*)(Abr + i * 2048);
#pragma unroll
        for (int i = 0; i < 32; i++) {
          const int sw = (((i * 4) + lk3) ^ x7) << 3;
          ah = mfma_bf16(av[i], *(short8v*)&wlds[lbH + sw], ah);
        }
      }
      u16* htile = h0P + (size_t)(t + 1) * BH + (size_t)cg * 1024;
#pragma unroll
      for (int v = 0; v < 4; v++) {
        float th = tanhf(ah[v] + xh[v]);
        float hn = (1.f - zreg[v]) * hreg[v] + zreg[v] * th;
        hreg[v] = hn;
        u16 me = f2bf(hn);
        int oth = __shfl_xor((int)me, 1);
        if (!(dcol & 1)) {
          u32 pk = (u32)me | ((u32)(u16)oth << 16);
          __hip_atomic_store((u32*)(htile + (orow + v) * 16 + dcol), pk,
                             __ATOMIC_RELAXED, __HIP_MEMORY_SCOPE_AGENT);
        }
        if (t == T_ - 1)
          hfin[(size_t)(orow + v) * 1024 + jr + dcol] = hn;
      }
      asm volatile("s_waitcnt vmcnt(0)" ::: "memory");
      __syncthreads();
      if (tid == 0)
        __hip_atomic_store(myslot, 2 * t + 2, __ATOMIC_RELAXED, __HIP_MEMORY_SCOPE_AGENT);
    }
  } else {
    // ================= layer 1 =================
    float bR = bias1[jr + dcol];
    float bZ = bias1[1024 + jr + dcol];
    float bH = bias1[2048 + jr + dcol];
    if (tid == 0) waitge(bcast0, 2);  // h0[1] ready before first A-part1
    __syncthreads();
    for (int t = 0; t < T_; t++) {
      float zreg[4];
      const u16* Ab0 = h0P + (size_t)(t + 1) * BH + abase;
      // ---- A part 1: h0[t+1] half (burst; dep satisfied by prev iter's wait) ----
      f32x4 ar = {}, az = {};
      {
        short8v av[32];
#pragma unroll
        for (int i = 0; i < 32; i++) av[i] = *(const short8v*)(Ab0 + i * 2048);
#pragma unroll
        for (int i = 0; i < 32; i++) {
          const int sw = ((128 + i * 4 + lk3) ^ x7) << 3;
          ar = mfma_bf16(av[i], *(short8v*)&wlds[lbR + sw], ar);
          az = mfma_bf16(av[i], *(short8v*)&wlds[lbZ + sw], az);
        }
      }
      // ---- wait: h1[t] visible; keep L0 2 steps ahead for next iter ----
      if (tid == 0) {
        if (t) waitge(bcast1, 2 * t);
        int tgt = 2 * (t + 2);
        waitge(bcast0, tgt > 2 * T_ ? 2 * T_ : tgt);
      }
      __syncthreads();
      // ---- A part 2: h1[t] half (burst) ----
      {
        const u16* Ab1 = h1P + (size_t)t * BH + abase;
        short8v av[32];
#pragma unroll
        for (int i = 0; i < 32; i++) av[i] = *(const short8v*)(Ab1 + i * 2048);
#pragma unroll
        for (int i = 0; i < 32; i++) {
          const int sw = ((i * 4 + lk3) ^ x7) << 3;
          ar = mfma_bf16(av[i], *(short8v*)&wlds[lbR + sw], ar);
          az = mfma_bf16(av[i], *(short8v*)&wlds[lbZ + sw], az);
        }
      }
      u16* rtile = r1P + (size_t)t * BH + (size_t)cg * 1024;
#pragma unroll
      for (int v = 0; v < 4; v++) {
        float r = 1.f / (1.f + __expf(-(ar[v] + bR)));
        float z = 1.f / (1.f + __expf(-(az[v] + bZ)));
        zreg[v] = z;
        u16 me = f2bf(r * hreg[v]);
        int oth = __shfl_xor((int)me, 1);
        if (!(dcol & 1)) {
          u32 pk = (u32)me | ((u32)(u16)oth << 16);
          __hip_atomic_store((u32*)(rtile + (orow + v) * 16 + dcol), pk,
                             __ATOMIC_RELAXED, __HIP_MEMORY_SCOPE_AGENT);
        }
      }
      asm volatile("s_waitcnt vmcnt(0)" ::: "memory");
      __syncthreads();
      if (tid == 0)
        __hip_atomic_store(myslot, 2 * t + 1, __ATOMIC_RELAXED, __HIP_MEMORY_SCOPE_AGENT);
      // ---- B part 1: h0[t+1] half (burst; L2-warm after stage A) ----
      f32x4 ah = {};
      {
        short8v av[32];
#pragma unroll
        for (int i = 0; i < 32; i++) av[i] = *(const short8v*)(Ab0 + i * 2048);
#pragma unroll
        for (int i = 0; i < 32; i++)
          ah = mfma_bf16(av[i], *(const short8v*)(Whg + 1024 + i * 32), ah);
      }
      // ---- wait: rh1[t] visible ----
      if (tid == 0) waitge(bcast1, 2 * t + 1);
      __syncthreads();
      // ---- B part 2: rh1[t] half (burst) ----
      {
        const u16* Abr = r1P + (size_t)t * BH + abase;
        short8v av[32];
#pragma unroll
        for (int i = 0; i < 32; i++) av[i] = *(const short8v*)(Abr + i * 2048);
#pragma unroll
        for (int i = 0; i < 32; i++)
          ah = mfma_bf16(av[i], *(const short8v*)(Whg + i * 32), ah);
      }
      u16* htile = h1P + (size_t)(t + 1) * BH + (size_t)cg * 1024;
#pragma unroll
      for (int v = 0; v < 4; v++) {
        float th = tanhf(ah[v] + bH);
        float hn = (1.f - zreg[v]) * hreg[v] + zreg[v] * th;
        hreg[v] = hn;
        u16 me = f2bf(hn);
        int oth = __shfl_xor((int)me, 1);
        if (!(dcol & 1)) {
          u32 pk = (u32)me | ((u32)(u16)oth << 16);
          __hip_atomic_store((u32*)(htile + (orow + v) * 16 + dcol), pk,
                             __ATOMIC_RELAXED, __HIP_MEMORY_SCOPE_AGENT);
        }
        if (t == T_ - 1)
          hfin[(size_t)BH + (size_t)(orow + v) * 1024 + jr + dcol] = hn;
      }
      asm volatile("s_waitcnt vmcnt(0)" ::: "memory");
      __syncthreads();
      if (tid == 0)
        __hip_atomic_store(myslot, 2 * t + 2, __ATOMIC_RELAXED, __HIP_MEMORY_SCOPE_AGENT);
    }
  }
}

// ---------------- launcher ----------------

extern "C" void kernel_launch(void* const* d_in, const int* in_sizes, int n_in,
                              void* d_out, int out_size, void* d_ws, size_t ws_size,
                              hipStream_t stream) {
  const int* inputs = (const int*)d_in[0];
  const float* hidden = (const float*)d_in[1];
  const float* emb = (const float*)d_in[2];
  const float* Wr0 = (const float*)d_in[3];
  const float* Wz0 = (const float*)d_in[4];
  const float* Wh0 = (const float*)d_in[5];
  const float* WrR = (const float*)d_in[6];
  const float* WzR = (const float*)d_in[7];
  const float* WhR = (const float*)d_in[8];
  const float* brR = (const float*)d_in[9];
  const float* bzR = (const float*)d_in[10];
  const float* bhR = (const float*)d_in[11];
  const float* Ur = (const float*)d_in[12];
  const float* Uz = (const float*)d_in[13];
  const float* Uh = (const float*)d_in[14];
  const float* bur = (const float*)d_in[15];
  const float* buz = (const float*)d_in[16];
  const float* buh = (const float*)d_in[17];
  const float* Wout = (const float*)d_in[18];
  const float* bout = (const float*)d_in[19];
  float* out = (float*)d_out;

  char* ws = (char*)d_ws;
  size_t off = 0;
  auto alloc = [&](size_t bytes) -> void* {
    void* p = ws + off;
    off += (bytes + 255) & ~(size_t)255;
    return p;
  };
  u16* x_bf  = (u16*)alloc((size_t)TB * E_ * 2);
  u16* W0cat = (u16*)alloc((size_t)3072 * 512 * 2);
  u16* U0cat = (u16*)alloc((size_t)3072 * 1024 * 2);
  u16* U1W   = (u16*)alloc((size_t)3072 * 2048 * 2);
  u16* Woutb = (u16*)alloc((size_t)V_ * H_ * 2);
  float* bias0 = (float*)alloc(3072 * 4);
  float* bias1 = (float*)alloc(3072 * 4);
  u16* XP    = (u16*)alloc((size_t)TB * 3072 * 2);
  u16* h0P   = (u16*)alloc((size_t)(T_ + 1) * BH * 2);
  u16* h1P   = (u16*)alloc((size_t)(T_ + 1) * BH * 2);
  u16* r0P   = (u16*)alloc((size_t)T_ * BH * 2);
  u16* r1P   = (u16*)alloc((size_t)T_ * BH * 2);
  int* flags = (int*)alloc(32768);
  (void)ws_size; (void)in_sizes; (void)n_in; (void)out_size;

  hipMemsetAsync(flags, 0, 32768, stream);

  k_prepall<<<2048, 256, 0, stream>>>(Wr0, Wz0, Wh0, Ur, Uz, Uh, WrR, WzR, WhR, Wout,
                                      W0cat, U0cat, U1W, Woutb);
  k_gather<<<TB * E_ / 256, 256, 0, stream>>>(inputs, emb, x_bf);
  k_bias<<<12, 256, 0, stream>>>(bur, buz, buh, brR, bzR, bhR, bias0, bias1);
  k_init<<<256, 256, 0, stream>>>(hidden, h0P, h1P);

  k_gemmX<<<dim3(32, 24), 256, 0, stream>>>(x_bf, W0cat, bias0, XP);
  k_recur<<<130, 256, 0, stream>>>(U0cat, U1W, XP, bias1, hidden, h0P, h1P,
                                   r0P, r1P, flags, out + (size_t)TB * V_);
  k_gemmL<<<2560, 256, 0, stream>>>(h1P + BH, Woutb, bout, out);
}

// Round 13
// 1389.476 us; speedup vs baseline: 12.8157x; 1.0573x over previous
//
#include <hip/hip_runtime.h>
#include <hip/hip_bf16.h>

#define T_ 64
#define B_ 64
#define E_ 512
#define H_ 1024
#define V_ 10000
#define TB 4096   // T_*B_
#define BH 65536  // B_*H_

typedef unsigned short u16;
typedef unsigned int u32;
typedef unsigned long long u64;
typedef __attribute__((ext_vector_type(8))) short short8v;
typedef __attribute__((ext_vector_type(4))) float f32x4;

__device__ inline f32x4 mfma_bf16(short8v a, short8v b, f32x4 c) {
  return __builtin_amdgcn_mfma_f32_16x16x32_bf16(a, b, c, 0, 0, 0);
}

__device__ inline u16 f2bf(float f) {
  unsigned u = __float_as_uint(f);
  unsigned r = (u + 0x7fffu + ((u >> 16) & 1u)) >> 16;
  return (u16)r;
}
__device__ inline float bf2f(u16 h) { return __uint_as_float(((unsigned)h) << 16); }

// ---------------- prep ----------------

__global__ void k_prepall(const float* __restrict__ Wr0, const float* __restrict__ Wz0,
                          const float* __restrict__ Wh0, const float* __restrict__ Ur,
                          const float* __restrict__ Uz, const float* __restrict__ Uh,
                          const float* __restrict__ WrR, const float* __restrict__ WzR,
                          const float* __restrict__ WhR, const float* __restrict__ Wout,
                          u16* __restrict__ W0cat, u16* __restrict__ U0cat,
                          u16* __restrict__ U1W, u16* __restrict__ Woutb) {
  const int HE = H_ * E_;
  const int HH = H_ * H_;
  const size_t n0 = 3u * (size_t)HE;
  const size_t n1 = n0 + 3u * (size_t)HH;
  const size_t n2 = n1 + 3072u * 2048u;
  const size_t n3 = n2 + (size_t)V_ * H_;
  size_t i = (size_t)blockIdx.x * 256 + threadIdx.x;
  const size_t stride = (size_t)gridDim.x * 256;
  for (; i < n3; i += stride) {
    if (i < n0) {
      int g = (int)(i >> 19), off = (int)(i & (HE - 1));
      const float* s = g == 0 ? Wr0 : (g == 1 ? Wz0 : Wh0);
      W0cat[i] = f2bf(s[off]);
    } else if (i < n1) {
      size_t j = i - n0;
      int g = (int)(j >> 20), off = (int)(j & (HH - 1));
      const float* s = g == 0 ? Ur : (g == 1 ? Uz : Uh);
      U0cat[j] = f2bf(s[off]);
    } else if (i < n2) {
      size_t k = i - n1;
      int row = (int)(k >> 11), kk = (int)(k & 2047);
      int g = row >> 10, jj = row & 1023;
      const float* su = g == 0 ? Ur : (g == 1 ? Uz : Uh);
      const float* sw = g == 0 ? WrR : (g == 1 ? WzR : WhR);
      float v = (kk < 1024) ? su[(size_t)HH + (size_t)jj * 1024 + kk]
                            : sw[(size_t)jj * 1024 + (kk - 1024)];
      U1W[k] = f2bf(v);
    } else {
      size_t m = i - n2;
      Woutb[m] = f2bf(Wout[m]);
    }
  }
}

__global__ void k_gather(const int* __restrict__ idx, const float* __restrict__ emb,
                         u16* __restrict__ xbf) {
  int i = blockIdx.x * 256 + threadIdx.x;
  int row = i >> 9, e = i & 511;
  xbf[i] = f2bf(emb[(size_t)idx[row] * E_ + e]);
}

__global__ void k_bias(const float* __restrict__ bur, const float* __restrict__ buz,
                       const float* __restrict__ buh, const float* __restrict__ brR,
                       const float* __restrict__ bzR, const float* __restrict__ bhR,
                       float* __restrict__ bias0, float* __restrict__ bias1) {
  int j = blockIdx.x * 256 + threadIdx.x;
  int seg = j >> 10, col = j & 1023;
  float b0, b1;
  if (seg == 0)      { b0 = bur[col]; b1 = brR[col] + bur[H_ + col]; }
  else if (seg == 1) { b0 = buz[col]; b1 = bzR[col] + buz[H_ + col]; }
  else               { b0 = buh[col]; b1 = bhR[col] + buh[H_ + col]; }
  bias0[j] = b0; bias1[j] = b1;
}

// init packed hist slabs at t=0: dst[(j>>4)*1024 + row*16 + (j&15)]
__global__ void k_init(const float* __restrict__ hidden, u16* __restrict__ h0P,
                       u16* __restrict__ h1P) {
  int i = blockIdx.x * 256 + threadIdx.x;
  int row = i >> 10, j = i & 1023;
  int dst = ((j >> 4) << 10) + (row << 4) + (j & 15);
  h0P[dst] = f2bf(hidden[i]);
  h1P[dst] = f2bf(hidden[BH + i]);
}

// ---------------- GEMM 1: X = x_emb @ W0cat^T + bias0, packed-X bf16 out ----------------

__global__ __launch_bounds__(256, 2) void k_gemmX(const u16* __restrict__ A,
                                                  const u16* __restrict__ Wt,
                                                  const float* __restrict__ bias,
                                                  u16* __restrict__ XP) {
  const int m0 = blockIdx.x * 128, n0 = blockIdx.y * 128;
  const int wid = threadIdx.x >> 6, lane = threadIdx.x & 63;
  const int wm = wid >> 1, wn = wid & 1;
  const int lrow = lane & 15, lk = (lane >> 4) * 8;
  f32x4 acc[4][4] = {};
  const u16* Ab = A + (size_t)(m0 + wm * 64 + lrow) * 512 + lk;
  const u16* Wb = Wt + (size_t)(n0 + wn * 64 + lrow) * 512 + lk;
  for (int ks = 0; ks < 512; ks += 32) {
    short8v a[4], b[4];
#pragma unroll
    for (int f = 0; f < 4; f++) a[f] = *(const short8v*)(Ab + (size_t)f * 16 * 512 + ks);
#pragma unroll
    for (int f = 0; f < 4; f++) b[f] = *(const short8v*)(Wb + (size_t)f * 16 * 512 + ks);
#pragma unroll
    for (int i = 0; i < 4; i++)
#pragma unroll
      for (int j = 0; j < 4; j++) acc[i][j] = mfma_bf16(a[i], b[j], acc[i][j]);
  }
  const int drow0 = (lane >> 4) * 4, dcol = lane & 15;
#pragma unroll
  for (int i = 0; i < 4; i++)
#pragma unroll
    for (int j = 0; j < 4; j++) {
      int col = n0 + wn * 64 + j * 16 + dcol;
      float bv = bias[col];
      int g = col >> 10, cg = (col & 1023) >> 4, cc = col & 15;
#pragma unroll
      for (int v = 0; v < 4; v++) {
        int row = m0 + wm * 64 + i * 16 + drow0 + v;
        int t = row >> 6, rr = row & 63;
        XP[(((size_t)t * 64 + cg) * 64 + rr) * 48 + g * 16 + cc] = f2bf(acc[i][j][v] + bv);
      }
    }
}

// ---------------- GEMM 2: logits, XCD-affine N-partitioning ----------------

__global__ __launch_bounds__(256, 2) void k_gemmL(const u16* __restrict__ AP,
                                                  const u16* __restrict__ Wt,
                                                  const float* __restrict__ bias,
                                                  float* __restrict__ C) {
  const int xcd = blockIdx.x & 7, idx = blockIdx.x >> 3;
  const int nt = xcd * 10 + (idx % 10);
  const int mt = idx / 10;
  if (nt >= 79) return;
  const int m0 = mt * 128, n0 = nt * 128;
  const int wid = threadIdx.x >> 6, lane = threadIdx.x & 63;
  const int wm = wid >> 1, wn = wid & 1;
  const int lrow = lane & 15, lk = (lane >> 4) * 8;
  const int lkb = lk >> 4, lkc = lk & 15;
  f32x4 acc[4][4] = {};
  const int rowhi = (m0 + wm * 64) >> 6;
  const u16* Ab = AP + (size_t)rowhi * BH + (size_t)lkb * 1024 + lrow * 16 + lkc;
  const u16* Wb = Wt + (size_t)(n0 + wn * 64 + lrow) * 1024 + lk;
  bool nvalid[4];
#pragma unroll
  for (int f = 0; f < 4; f++) nvalid[f] = (n0 + wn * 64 + f * 16 + lrow) < V_;
  const short8v zv = {};
  for (int ks = 0; ks < 1024; ks += 32) {
    short8v a[4], b[4];
#pragma unroll
    for (int f = 0; f < 4; f++) a[f] = *(const short8v*)(Ab + ks * 64 + f * 256);
#pragma unroll
    for (int f = 0; f < 4; f++)
      b[f] = nvalid[f] ? *(const short8v*)(Wb + (size_t)f * 16 * 1024 + ks) : zv;
#pragma unroll
    for (int i = 0; i < 4; i++)
#pragma unroll
      for (int j = 0; j < 4; j++) acc[i][j] = mfma_bf16(a[i], b[j], acc[i][j]);
  }
  const int drow0 = (lane >> 4) * 4, dcol = lane & 15;
#pragma unroll
  for (int i = 0; i < 4; i++)
#pragma unroll
    for (int j = 0; j < 4; j++) {
      int col = n0 + wn * 64 + j * 16 + dcol;
      if (col >= V_) continue;
      float bv = bias[col];
#pragma unroll
      for (int v = 0; v < 4; v++) {
        int row = m0 + wm * 64 + i * 16 + drow0 + v;
        C[(size_t)row * V_ + col] = acc[i][j][v] + bv;
      }
    }
}

// ---------------- recurrence: burst loads + DIRECT consumer polling ----------------
// 128 blocks x 256 thr. gbid<64: L0 (cg=gbid); 64..127: L1. No aggregator.
// Producers: publish tile -> vmcnt(0) -> leader stores phase to private slot.
// Consumers: leader WAVE (tid<64) polls all 64 slots (lane i -> slot i, ballot).
// L1 holds A-part1's h0 burst in registers across the wait and reuses it in B-part1.

__device__ inline void pollall(const int* slots, int tgt) {
  const int lane = threadIdx.x & 63;
  const int* p = slots + lane * 32;
  for (;;) {
    int v = __hip_atomic_load(p, __ATOMIC_RELAXED, __HIP_MEMORY_SCOPE_AGENT);
    if (__all(v >= tgt)) break;
    __builtin_amdgcn_s_sleep(2);
  }
}

__global__ __launch_bounds__(256, 1) void k_recur(
    const u16* __restrict__ U0, const u16* __restrict__ U1W,
    const u16* __restrict__ XP, const float* __restrict__ bias1,
    const float* __restrict__ hidden,
    u16* __restrict__ h0P, u16* __restrict__ h1P,
    u16* __restrict__ r0P, u16* __restrict__ r1P,
    int* __restrict__ flags, float* __restrict__ hfin) {
  __shared__ __align__(16) u16 wlds[65536];  // 128 KiB

  const int tid = threadIdx.x, gbid = blockIdx.x;
  const int lay = gbid >> 6;
  const int cg = gbid & 63;
  const int jr = cg * 16;
  const int wid = tid >> 6, lane = tid & 63;
  const int lrow = lane & 15, lk = (lane >> 4) * 8;
  const int lk3 = lk >> 3, x7 = lrow & 7;
  const int drow0 = (lane >> 4) * 4, dcol = lane & 15;
  const int abase = (lk >> 4) * 1024 + (wid * 16 + lrow) * 16 + (lk & 15);
  const int KLS = lay ? 11 : 10;
  int* f0s = flags;          // 64 slots x 32 ints
  int* f1s = flags + 2048;
  int* myslot = (lay ? f1s : f0s) + cg * 32;

  {  // stage weights into LDS (swizzled 16B chunks)
    const u16* Wg = lay ? U1W : U0;
    const int lCPR = lay ? 8 : 7;
    const int NG = lay ? 2 : 3;
    const int total = NG << (4 + lCPR);
    const int KL = 1 << KLS;
    for (int idx = tid; idx < total; idx += 256) {
      int r16 = idx >> lCPR;
      int ch = idx & ((1 << lCPR) - 1);
      int g = r16 >> 4, r = r16 & 15;
      short8v v = *(const short8v*)(Wg + (size_t)((g << 10) + jr + r) * KL + (ch << 3));
      *(short8v*)&wlds[((size_t)r16 << KLS) + ((ch ^ (r & 7)) << 3)] = v;
    }
  }
  __syncthreads();

  const int lbR = lrow << KLS;
  const int lbZ = (16 + lrow) << KLS;
  const int lbH = (32 + lrow) << KLS;  // L0 only
  const u16* Whg = U1W + (size_t)(2048 + jr + lrow) * 2048 + lk;  // L1 Wh (global)
  const int orow = wid * 16 + drow0;

  float hreg[4];
#pragma unroll
  for (int v = 0; v < 4; v++)
    hreg[v] = hidden[(size_t)lay * BH + (size_t)(orow + v) * 1024 + jr + dcol];

  if (!lay) {
    // ================= layer 0 =================
    for (int t = 0; t < T_; t++) {
      float xr[4], xz[4], xh[4], zreg[4];
      const u16* xb = XP + (((size_t)t * 64 + cg) * 64 + orow) * 48 + dcol;
#pragma unroll
      for (int v = 0; v < 4; v++) {
        xr[v] = bf2f(xb[v * 48]);
        xz[v] = bf2f(xb[v * 48 + 16]);
        xh[v] = bf2f(xb[v * 48 + 32]);
      }
      if (t) { if (tid < 64) pollall(f0s, 2 * t); __syncthreads(); }
      // stage A: burst-load h0[t], then MFMA
      f32x4 ar = {}, az = {};
      {
        const u16* Ab = h0P + (size_t)t * BH + abase;
        short8v av[32];
#pragma unroll
        for (int i = 0; i < 32; i++) av[i] = *(const short8v*)(Ab + i * 2048);
#pragma unroll
        for (int i = 0; i < 32; i++) {
          const int sw = (((i * 4) + lk3) ^ x7) << 3;
          ar = mfma_bf16(av[i], *(short8v*)&wlds[lbR + sw], ar);
          az = mfma_bf16(av[i], *(short8v*)&wlds[lbZ + sw], az);
        }
      }
      u16* rtile = r0P + (size_t)t * BH + (size_t)cg * 1024;
#pragma unroll
      for (int v = 0; v < 4; v++) {
        float r = 1.f / (1.f + __expf(-(ar[v] + xr[v])));
        float z = 1.f / (1.f + __expf(-(az[v] + xz[v])));
        zreg[v] = z;
        u16 me = f2bf(r * hreg[v]);
        int oth = __shfl_xor((int)me, 1);
        if (!(dcol & 1)) {
          u32 pk = (u32)me | ((u32)(u16)oth << 16);
          __hip_atomic_store((u32*)(rtile + (orow + v) * 16 + dcol), pk,
                             __ATOMIC_RELAXED, __HIP_MEMORY_SCOPE_AGENT);
        }
      }
      asm volatile("s_waitcnt vmcnt(0)" ::: "memory");
      __syncthreads();
      if (tid == 0)
        __hip_atomic_store(myslot, 2 * t + 1, __ATOMIC_RELAXED, __HIP_MEMORY_SCOPE_AGENT);
      if (tid < 64) pollall(f0s, 2 * t + 1);
      __syncthreads();
      // stage B: burst-load rh0[t], then MFMA
      f32x4 ah = {};
      {
        const u16* Abr = r0P + (size_t)t * BH + abase;
        short8v av[32];
#pragma unroll
        for (int i = 0; i < 32; i++) av[i] = *(const short8v*)(Abr + i * 2048);
#pragma unroll
        for (int i = 0; i < 32; i++) {
          const int sw = (((i * 4) + lk3) ^ x7) << 3;
          ah = mfma_bf16(av[i], *(short8v*)&wlds[lbH + sw], ah);
        }
      }
      u16* htile = h0P + (size_t)(t + 1) * BH + (size_t)cg * 1024;
#pragma unroll
      for (int v = 0; v < 4; v++) {
        float th = tanhf(ah[v] + xh[v]);
        float hn = (1.f - zreg[v]) * hreg[v] + zreg[v] * th;
        hreg[v] = hn;
        u16 me = f2bf(hn);
        int oth = __shfl_xor((int)me, 1);
        if (!(dcol & 1)) {
          u32 pk = (u32)me | ((u32)(u16)oth << 16);
          __hip_atomic_store((u32*)(htile + (orow + v) * 16 + dcol), pk,
                             __ATOMIC_RELAXED, __HIP_MEMORY_SCOPE_AGENT);
        }
        if (t == T_ - 1)
          hfin[(size_t)(orow + v) * 1024 + jr + dcol] = hn;
      }
      asm volatile("s_waitcnt vmcnt(0)" ::: "memory");
      __syncthreads();
      if (tid == 0)
        __hip_atomic_store(myslot, 2 * t + 2, __ATOMIC_RELAXED, __HIP_MEMORY_SCOPE_AGENT);
    }
  } else {
    // ================= layer 1 =================
    float bR = bias1[jr + dcol];
    float bZ = bias1[1024 + jr + dcol];
    float bH = bias1[2048 + jr + dcol];
    if (tid < 64) pollall(f0s, 2);  // h0[1] ready before first A-part1
    __syncthreads();
    for (int t = 0; t < T_; t++) {
      float zreg[4];
      const u16* Ab0 = h0P + (size_t)(t + 1) * BH + abase;
      // ---- A part 1: h0[t+1] half (burst; registers av0 kept for B-part1) ----
      f32x4 ar = {}, az = {};
      short8v av0[32];
#pragma unroll
      for (int i = 0; i < 32; i++) av0[i] = *(const short8v*)(Ab0 + i * 2048);
#pragma unroll
      for (int i = 0; i < 32; i++) {
        const int sw = ((128 + i * 4 + lk3) ^ x7) << 3;
        ar = mfma_bf16(av0[i], *(short8v*)&wlds[lbR + sw], ar);
        az = mfma_bf16(av0[i], *(short8v*)&wlds[lbZ + sw], az);
      }
      // ---- wait: h1[t] visible; keep L0 2 steps ahead for next iter ----
      if (tid < 64) {
        if (t) pollall(f1s, 2 * t);
        int tgt = 2 * (t + 2);
        pollall(f0s, tgt > 2 * T_ ? 2 * T_ : tgt);
      }
      __syncthreads();
      // ---- A part 2: h1[t] half (burst) ----
      {
        const u16* Ab1 = h1P + (size_t)t * BH + abase;
        short8v av[32];
#pragma unroll
        for (int i = 0; i < 32; i++) av[i] = *(const short8v*)(Ab1 + i * 2048);
#pragma unroll
        for (int i = 0; i < 32; i++) {
          const int sw = ((i * 4 + lk3) ^ x7) << 3;
          ar = mfma_bf16(av[i], *(short8v*)&wlds[lbR + sw], ar);
          az = mfma_bf16(av[i], *(short8v*)&wlds[lbZ + sw], az);
        }
      }
      u16* rtile = r1P + (size_t)t * BH + (size_t)cg * 1024;
#pragma unroll
      for (int v = 0; v < 4; v++) {
        float r = 1.f / (1.f + __expf(-(ar[v] + bR)));
        float z = 1.f / (1.f + __expf(-(az[v] + bZ)));
        zreg[v] = z;
        u16 me = f2bf(r * hreg[v]);
        int oth = __shfl_xor((int)me, 1);
        if (!(dcol & 1)) {
          u32 pk = (u32)me | ((u32)(u16)oth << 16);
          __hip_atomic_store((u32*)(rtile + (orow + v) * 16 + dcol), pk,
                             __ATOMIC_RELAXED, __HIP_MEMORY_SCOPE_AGENT);
        }
      }
      asm volatile("s_waitcnt vmcnt(0)" ::: "memory");
      __syncthreads();
      if (tid == 0)
        __hip_atomic_store(myslot, 2 * t + 1, __ATOMIC_RELAXED, __HIP_MEMORY_SCOPE_AGENT);
      // ---- B part 1: h0[t+1] half — REUSE av0 registers, stream Wh weights (hides wait) ----
      f32x4 ah = {};
#pragma unroll
      for (int i = 0; i < 32; i++)
        ah = mfma_bf16(av0[i], *(const short8v*)(Whg + 1024 + i * 32), ah);
      // ---- wait: rh1[t] visible ----
      if (tid < 64) pollall(f1s, 2 * t + 1);
      __syncthreads();
      // ---- B part 2: rh1[t] half (burst) ----
      {
        const u16* Abr = r1P + (size_t)t * BH + abase;
        short8v av[32];
#pragma unroll
        for (int i = 0; i < 32; i++) av[i] = *(const short8v*)(Abr + i * 2048);
#pragma unroll
        for (int i = 0; i < 32; i++)
          ah = mfma_bf16(av[i], *(const short8v*)(Whg + i * 32), ah);
      }
      u16* htile = h1P + (size_t)(t + 1) * BH + (size_t)cg * 1024;
#pragma unroll
      for (int v = 0; v < 4; v++) {
        float th = tanhf(ah[v] + bH);
        float hn = (1.f - zreg[v]) * hreg[v] + zreg[v] * th;
        hreg[v] = hn;
        u16 me = f2bf(hn);
        int oth = __shfl_xor((int)me, 1);
        if (!(dcol & 1)) {
          u32 pk = (u32)me | ((u32)(u16)oth << 16);
          __hip_atomic_store((u32*)(htile + (orow + v) * 16 + dcol), pk,
                             __ATOMIC_RELAXED, __HIP_MEMORY_SCOPE_AGENT);
        }
        if (t == T_ - 1)
          hfin[(size_t)BH + (size_t)(orow + v) * 1024 + jr + dcol] = hn;
      }
      asm volatile("s_waitcnt vmcnt(0)" ::: "memory");
      __syncthreads();
      if (tid == 0)
        __hip_atomic_store(myslot, 2 * t + 2, __ATOMIC_RELAXED, __HIP_MEMORY_SCOPE_AGENT);
    }
  }
}

// ---------------- launcher ----------------

extern "C" void kernel_launch(void* const* d_in, const int* in_sizes, int n_in,
                              void* d_out, int out_size, void* d_ws, size_t ws_size,
                              hipStream_t stream) {
  const int* inputs = (const int*)d_in[0];
  const float* hidden = (const float*)d_in[1];
  const float* emb = (const float*)d_in[2];
  const float* Wr0 = (const float*)d_in[3];
  const float* Wz0 = (const float*)d_in[4];
  const float* Wh0 = (const float*)d_in[5];
  const float* WrR = (const float*)d_in[6];
  const float* WzR = (const float*)d_in[7];
  const float* WhR = (const float*)d_in[8];
  const float* brR = (const float*)d_in[9];
  const float* bzR = (const float*)d_in[10];
  const float* bhR = (const float*)d_in[11];
  const float* Ur = (const float*)d_in[12];
  const float* Uz = (const float*)d_in[13];
  const float* Uh = (const float*)d_in[14];
  const float* bur = (const float*)d_in[15];
  const float* buz = (const float*)d_in[16];
  const float* buh = (const float*)d_in[17];
  const float* Wout = (const float*)d_in[18];
  const float* bout = (const float*)d_in[19];
  float* out = (float*)d_out;

  char* ws = (char*)d_ws;
  size_t off = 0;
  auto alloc = [&](size_t bytes) -> void* {
    void* p = ws + off;
    off += (bytes + 255) & ~(size_t)255;
    return p;
  };
  u16* x_bf  = (u16*)alloc((size_t)TB * E_ * 2);
  u16* W0cat = (u16*)alloc((size_t)3072 * 512 * 2);
  u16* U0cat = (u16*)alloc((size_t)3072 * 1024 * 2);
  u16* U1W   = (u16*)alloc((size_t)3072 * 2048 * 2);
  u16* Woutb = (u16*)alloc((size_t)V_ * H_ * 2);
  float* bias0 = (float*)alloc(3072 * 4);
  float* bias1 = (float*)alloc(3072 * 4);
  u16* XP    = (u16*)alloc((size_t)TB * 3072 * 2);
  u16* h0P   = (u16*)alloc((size_t)(T_ + 1) * BH * 2);
  u16* h1P   = (u16*)alloc((size_t)(T_ + 1) * BH * 2);
  u16* r0P   = (u16*)alloc((size_t)T_ * BH * 2);
  u16* r1P   = (u16*)alloc((size_t)T_ * BH * 2);
  int* flags = (int*)alloc(32768);
  (void)ws_size; (void)in_sizes; (void)n_in; (void)out_size;

  hipMemsetAsync(flags, 0, 32768, stream);

  k_prepall<<<2048, 256, 0, stream>>>(Wr0, Wz0, Wh0, Ur, Uz, Uh, WrR, WzR, WhR, Wout,
                                      W0cat, U0cat, U1W, Woutb);
  k_gather<<<TB * E_ / 256, 256, 0, stream>>>(inputs, emb, x_bf);
  k_bias<<<12, 256, 0, stream>>>(bur, buz, buh, brR, bzR, bhR, bias0, bias1);
  k_init<<<256, 256, 0, stream>>>(hidden, h0P, h1P);

  k_gemmX<<<dim3(32, 24), 256, 0, stream>>>(x_bf, W0cat, bias0, XP);
  k_recur<<<128, 256, 0, stream>>>(U0cat, U1W, XP, bias1, hidden, h0P, h1P,
                                   r0P, r1P, flags, out + (size_t)TB * V_);
  k_gemmL<<<2560, 256, 0, stream>>>(h1P + BH, Woutb, bout, out);
}